// Round 2
// baseline (428.708 us; speedup 1.0000x reference)
//
#include <hip/hip_runtime.h>

// MoE top-2, B=4 S=4096 D=1024 E=8.  router_mask/top_k unused (per reference).
//
// Crash-defense round: (a) never exceed ws_size (runtime tiers), (b) no
// hipMemsetAsync, (c) on-device dtype detection (bf16 vs fp32) for all inputs
// and the output, (d) GEMM core consumes canonical bf16 (Wt + in-stage cvt).
//
// Pipeline: zero counters -> detect dtype -> [T2] transpose We -> gating
// (top-2 logits, scatter token ids into 28 expert-pair lists) -> tile map ->
// pair GEMM: per block 128 tokens x 64 cols, shared A-tile, two accumulator
// sets (expert a / expert b), gate weights applied in epilogue:
//   out = wa*(x@Wa + be_a) + wb*(x@Wb + be_b)

#define TOK 16384
#define DIM 1024
#define NE 8
#define NPAIR 28

typedef __attribute__((ext_vector_type(8))) short bf16x8;
typedef __attribute__((ext_vector_type(4))) float f32x4;

// ---- ws layout ----
#define OFF_CNT    0u         // 32 ints (zeroed each launch)
#define OFF_NTILES 128u       // 1 int
#define OFF_FLAG   132u       // 1 int (1 = bf16 mode, 0 = fp32 mode)
#define OFF_TMAP   192u       // 160 ints
#define OFF_TOKW   1024u      // 16384 float2 (wa,wb per token)   -> ends 132096
#define OFF_PLIST  132096u    // 28*16384 ushort                  -> ends 1049600
#define OFF_WT     1049600u   // 8*1024*1024 bf16 (16 MiB)        -> ends 17826816
#define NEED_T3    1049600u
#define NEED_T2    17826816u

__device__ __forceinline__ float bf2f(unsigned short u) {
  union { unsigned int i; float f; } c; c.i = ((unsigned int)u) << 16; return c.f;
}
__device__ __forceinline__ unsigned short f2bf_rne(float f) {
  union { float f; unsigned int i; } c; c.f = f;
  unsigned int i = c.i + 0x7fffu + ((c.i >> 16) & 1u);
  return (unsigned short)(i >> 16);
}
// round-half-up pack of two floats to packed bf16x2 (cheap; used in hot path)
__device__ __forceinline__ unsigned int pk2(float lo, float hi) {
  union { float f; unsigned int i; } a, b; a.f = lo; b.f = hi;
  return ((b.i + 0x8000u) & 0xFFFF0000u) | ((a.i + 0x8000u) >> 16);
}

// ---------------- tiny helpers ----------------
__global__ void zero_counters(int* p) { if (threadIdx.x < 32) p[threadIdx.x] = 0; }

// dtype detector: bf16-packed dwords have a bf16 exponent in bits[14:7].
__global__ void detect_dtype(const unsigned int* __restrict__ xdw, int* __restrict__ flag) {
  __shared__ int h;
  if (threadIdx.x == 0) h = 0;
  __syncthreads();
  unsigned int idx = (threadIdx.x * 32749u + 7u) & 0x7FFFFFu;  // < 8,388,608 dwords (33.5MB: in-bounds for both dtypes)
  unsigned int b = (xdw[idx] >> 7) & 0xFFu;
  atomicAdd(&h, (b >= 112u && b <= 132u) ? 1 : 0);
  __syncthreads();
  if (threadIdx.x == 0) flag[0] = (h >= 128) ? 1 : 0;
}

// ---------------- W transpose: Wt[e][n][k] = bf16(We[e][k][n]) ----------------
__global__ __launch_bounds__(256) void transpose_W(const void* __restrict__ Wev,
                                                   unsigned short* __restrict__ Wt,
                                                   const int* __restrict__ flag) {
  const int isbf = *flag;
  __shared__ __align__(16) unsigned short tile[64 * 72];
  const int k0 = blockIdx.x * 64, n0 = blockIdx.y * 64;
  const size_t ebase = (size_t)blockIdx.z << 20;
  const int tid = threadIdx.x;
  const int r = tid >> 2;            // k-row 0..63
  const int off = (tid & 3) * 16;    // n offset
  unsigned short buf[16];
  if (isbf) {
    const unsigned short* s = (const unsigned short*)Wev + ebase + (size_t)(k0 + r) * DIM + n0 + off;
    *(uint4*)&buf[0] = *(const uint4*)s;
    *(uint4*)&buf[8] = *(const uint4*)(s + 8);
  } else {
    const float* s = (const float*)Wev + ebase + (size_t)(k0 + r) * DIM + n0 + off;
#pragma unroll
    for (int jj = 0; jj < 4; ++jj) {
      float4 f = *(const float4*)(s + jj * 4);
      buf[jj * 4 + 0] = f2bf_rne(f.x); buf[jj * 4 + 1] = f2bf_rne(f.y);
      buf[jj * 4 + 2] = f2bf_rne(f.z); buf[jj * 4 + 3] = f2bf_rne(f.w);
    }
  }
  *(uint4*)&tile[r * 72 + off] = *(uint4*)&buf[0];
  *(uint4*)&tile[r * 72 + off + 8] = *(uint4*)&buf[8];
  __syncthreads();
  const int n = tid >> 2, ko = (tid & 3) * 16;
  unsigned short obuf[16];
#pragma unroll
  for (int j = 0; j < 16; ++j) obuf[j] = tile[(ko + j) * 72 + n];
  unsigned short* dst = Wt + ebase + (size_t)(n0 + n) * DIM + k0 + ko;
  *(uint4*)dst = *(uint4*)&obuf[0];
  *(uint4*)(dst + 8) = *(uint4*)&obuf[8];
}

// ---------------- gating: one wave per token ----------------
__global__ __launch_bounds__(256) void gating(const void* __restrict__ xv,
                                              const void* __restrict__ Wgv,
                                              const void* __restrict__ bgv,
                                              const int* __restrict__ flag,
                                              int* __restrict__ cnt,
                                              unsigned short* __restrict__ plist,
                                              float2* __restrict__ tokw) {
  const int isbf = *flag;
  const int lane = threadIdx.x & 63;
  const int t = blockIdx.x * 4 + (threadIdx.x >> 6);
  float acc[NE];
#pragma unroll
  for (int e = 0; e < NE; ++e) acc[e] = 0.f;

  if (isbf) {
    const unsigned short* xp = (const unsigned short*)xv + (size_t)t * DIM + lane * 16;
#pragma unroll
    for (int u = 0; u < 2; ++u) {
      union { uint4 v; unsigned short s[8]; } xr; xr.v = *(const uint4*)(xp + u * 8);
#pragma unroll
      for (int j = 0; j < 8; ++j) {
        const int d = lane * 16 + u * 8 + j;
        union { uint4 v; unsigned short s[8]; } wg;
        wg.v = *(const uint4*)((const unsigned short*)Wgv + (size_t)d * 8);
        const float xf = bf2f(xr.s[j]);
#pragma unroll
        for (int e = 0; e < NE; ++e) acc[e] += xf * bf2f(wg.s[e]);
      }
    }
  } else {
    const float* xp = (const float*)xv + (size_t)t * DIM + lane * 16;
    float xr[16];
#pragma unroll
    for (int u = 0; u < 4; ++u) *(float4*)&xr[u * 4] = *(const float4*)(xp + u * 4);
#pragma unroll
    for (int j = 0; j < 16; ++j) {
      const int d = lane * 16 + j;
      const float* wr = (const float*)Wgv + (size_t)d * 8;
      float4 w0 = *(const float4*)wr, w1 = *(const float4*)(wr + 4);
      const float xf = xr[j];
      acc[0] += xf * w0.x; acc[1] += xf * w0.y; acc[2] += xf * w0.z; acc[3] += xf * w0.w;
      acc[4] += xf * w1.x; acc[5] += xf * w1.y; acc[6] += xf * w1.z; acc[7] += xf * w1.w;
    }
  }
#pragma unroll
  for (int m = 1; m < 64; m <<= 1) {
#pragma unroll
    for (int e = 0; e < NE; ++e) acc[e] += __shfl_xor(acc[e], m);
  }
  if (lane == 0) {
    if (isbf) {
      union { uint4 v; unsigned short s[8]; } bgv8; bgv8.v = *(const uint4*)bgv;
#pragma unroll
      for (int e = 0; e < NE; ++e) acc[e] += bf2f(bgv8.s[e]);
    } else {
      const float* bgp = (const float*)bgv;
#pragma unroll
      for (int e = 0; e < NE; ++e) acc[e] += bgp[e];
    }
    // top-2, lax.top_k tie semantics (lowest index wins -> strict >)
    int e0 = 0; float v0 = acc[0];
#pragma unroll
    for (int e = 1; e < NE; ++e) if (acc[e] > v0) { v0 = acc[e]; e0 = e; }
    int e1 = -1; float v1 = -3.4e38f;
#pragma unroll
    for (int e = 0; e < NE; ++e) if (e != e0 && acc[e] > v1) { v1 = acc[e]; e1 = e; }
    const int a = e0 < e1 ? e0 : e1;
    const int b = e0 < e1 ? e1 : e0;
    const float wa = (a == e0) ? v0 : v1;
    const float wb = (a == e0) ? v1 : v0;
    const int pidx = a * 7 - (a * (a - 1)) / 2 + (b - a - 1);  // 0..27
    const int pos = atomicAdd(&cnt[pidx], 1);
    plist[pidx * TOK + pos] = (unsigned short)t;
    tokw[t] = make_float2(wa, wb);
  }
}

// ---------------- tile map ----------------
__global__ void build_tiles(const int* __restrict__ cnt, int* __restrict__ tile_map,
                            int* __restrict__ ntiles) {
  if (threadIdx.x == 0 && blockIdx.x == 0) {
    int idx = 0;
    for (int p = 0; p < NPAIR; ++p) {
      int t = (cnt[p] + 127) >> 7;
      for (int i = 0; i < t; ++i) tile_map[idx++] = p | (i << 8);
    }
    ntiles[0] = idx;  // <= 16384/128 + 28 = 156
  }
}

// ---------------- pair GEMM ----------------
// Block 256 thr (4 waves): 128 tokens x 64 cols, K loop ks=0..1023 step 64.
// LDS: A[128][64] + Wa[64][64] + Wb[64][64], XOR-swizzled 16B chunks (no pad,
// 2-way bank aliasing max = free). TIER 2: W from pre-transposed bf16 Wt.
// TIER 3 (small ws): W transposed in-LDS from We each iter (slow, emergency).
template <int TIER>
__global__ __launch_bounds__(256, 3) void moe_gemm(
    const void* __restrict__ xv, const unsigned short* __restrict__ Wt,
    const void* __restrict__ Wev, const void* __restrict__ bev,
    const int* __restrict__ flag, const int* __restrict__ cnt,
    const unsigned short* __restrict__ plist, const float2* __restrict__ tokw,
    const int* __restrict__ ntiles, const int* __restrict__ tile_map,
    void* __restrict__ outv) {
  if ((int)blockIdx.y >= *ntiles) return;
  const int isbf = *flag;
  const int tm = tile_map[blockIdx.y];
  const int p = tm & 255;
  const int mt = tm >> 8;
  const int count = cnt[p];
  int a = 0, rem = p;
  while (rem >= 7 - a) { rem -= 7 - a; ++a; }
  const int ea = a, eb = a + 1 + rem;

  const int tid = threadIdx.x;
  const int lane = tid & 63;
  const int wv = tid >> 6;
  const int n0 = blockIdx.x * 64;

  __shared__ __align__(16) unsigned short Alds[128 * 64];
  __shared__ __align__(16) unsigned short Wlds[2][64 * 64];

  const int rb = tid >> 3;        // A rows rb + i*32
  const int c16 = tid & 7;        // 16B chunk within 64-elem row
  int tok4[4];
#pragma unroll
  for (int i = 0; i < 4; ++i) {
    const int rg = mt * 128 + rb + i * 32;
    tok4[i] = (rg < count) ? (int)plist[p * TOK + rg] : -1;
  }

  f32x4 accA[2][4], accB[2][4];
#pragma unroll
  for (int i = 0; i < 2; ++i)
#pragma unroll
    for (int j = 0; j < 4; ++j) { accA[i][j] = (f32x4){0,0,0,0}; accB[i][j] = (f32x4){0,0,0,0}; }

  for (int ks = 0; ks < DIM; ks += 64) {
    // ---- stage A (shared between both experts) ----
#pragma unroll
    for (int i = 0; i < 4; ++i) {
      const int r = rb + i * 32;
      uint4 v = make_uint4(0u, 0u, 0u, 0u);
      if (tok4[i] >= 0) {
        if (isbf) {
          v = *(const uint4*)((const unsigned short*)xv + (size_t)tok4[i] * DIM + ks + c16 * 8);
        } else {
          const float* xs = (const float*)xv + (size_t)tok4[i] * DIM + ks + c16 * 8;
          float4 f0 = *(const float4*)xs, f1 = *(const float4*)(xs + 4);
          v.x = pk2(f0.x, f0.y); v.y = pk2(f0.z, f0.w);
          v.z = pk2(f1.x, f1.y); v.w = pk2(f1.z, f1.w);
        }
      }
      *(uint4*)&Alds[r * 64 + ((c16 ^ (r & 7)) << 3)] = v;
    }
    // ---- stage W for both experts ----
    if (TIER == 2) {
#pragma unroll
      for (int h = 0; h < 2; ++h) {
        const size_t ebase = (size_t)(h ? eb : ea) << 20;
#pragma unroll
        for (int i = 0; i < 2; ++i) {
          const int r = (tid >> 3) + i * 32;  // col row 0..63
          uint4 w = *(const uint4*)(Wt + ebase + (size_t)(n0 + r) * DIM + ks + c16 * 8);
          *(uint4*)&Wlds[h][r * 64 + ((c16 ^ (r & 7)) << 3)] = w;
        }
      }
    } else {
      const int kk = tid >> 2;           // 0..63
      const int noff = (tid & 3) * 16;
#pragma unroll
      for (int h = 0; h < 2; ++h) {
        const size_t ebase = (size_t)(h ? eb : ea) << 20;
        unsigned short wb16[16];
        if (isbf) {
          const unsigned short* s = (const unsigned short*)Wev + ebase + (size_t)(ks + kk) * DIM + n0 + noff;
          *(uint4*)&wb16[0] = *(const uint4*)s;
          *(uint4*)&wb16[8] = *(const uint4*)(s + 8);
        } else {
          const float* s = (const float*)Wev + ebase + (size_t)(ks + kk) * DIM + n0 + noff;
#pragma unroll
          for (int jj = 0; jj < 4; ++jj) {
            float4 f = *(const float4*)(s + jj * 4);
            unsigned int lo = pk2(f.x, f.y), hi = pk2(f.z, f.w);
            wb16[jj * 4 + 0] = (unsigned short)(lo & 0xFFFF);
            wb16[jj * 4 + 1] = (unsigned short)(lo >> 16);
            wb16[jj * 4 + 2] = (unsigned short)(hi & 0xFFFF);
            wb16[jj * 4 + 3] = (unsigned short)(hi >> 16);
          }
        }
        const int chunk = kk >> 3, kin = kk & 7;
#pragma unroll
        for (int j = 0; j < 16; ++j) {
          const int n = noff + j;
          Wlds[h][n * 64 + ((chunk ^ (n & 7)) << 3) + kin] = wb16[j];
        }
      }
    }
    __syncthreads();
    // ---- MFMA ----
    const int row16 = lane & 15, quad = lane >> 4;
#pragma unroll
    for (int kst = 0; kst < 2; ++kst) {
      const int chunk = kst * 4 + quad;
      bf16x8 af[2];
#pragma unroll
      for (int rt = 0; rt < 2; ++rt) {
        const int r = wv * 32 + rt * 16 + row16;
        af[rt] = *(const bf16x8*)&Alds[r * 64 + ((chunk ^ (r & 7)) << 3)];
      }
#pragma unroll
      for (int ct = 0; ct < 4; ++ct) {
        const int n = ct * 16 + row16;
        const int wo = n * 64 + ((chunk ^ (n & 7)) << 3);
        bf16x8 bA = *(const bf16x8*)&Wlds[0][wo];
        bf16x8 bB = *(const bf16x8*)&Wlds[1][wo];
#pragma unroll
        for (int rt = 0; rt < 2; ++rt) {
          accA[rt][ct] = __builtin_amdgcn_mfma_f32_16x16x32_bf16(af[rt], bA, accA[rt][ct], 0, 0, 0);
          accB[rt][ct] = __builtin_amdgcn_mfma_f32_16x16x32_bf16(af[rt], bB, accB[rt][ct], 0, 0, 0);
        }
      }
    }
    __syncthreads();
  }

  // ---- epilogue: out = wa*(XA + be_a) + wb*(XB + be_b) ----
  // C layout: col = lane&15, row = (lane>>4)*4 + reg
  const int col_l = lane & 15, quad = lane >> 4;
  float bea[4], beb[4];
#pragma unroll
  for (int ct = 0; ct < 4; ++ct) {
    const int col = n0 + ct * 16 + col_l;
    if (isbf) {
      bea[ct] = bf2f(((const unsigned short*)bev)[ea * DIM + col]);
      beb[ct] = bf2f(((const unsigned short*)bev)[eb * DIM + col]);
    } else {
      bea[ct] = ((const float*)bev)[ea * DIM + col];
      beb[ct] = ((const float*)bev)[eb * DIM + col];
    }
  }
#pragma unroll
  for (int rt = 0; rt < 2; ++rt) {
#pragma unroll
    for (int j = 0; j < 4; ++j) {
      const int rg = mt * 128 + wv * 32 + rt * 16 + quad * 4 + j;
      if (rg < count) {
        const int tk = (int)plist[p * TOK + rg];
        const float2 w = tokw[tk];
#pragma unroll
        for (int ct = 0; ct < 4; ++ct) {
          const float o = w.x * (accA[rt][ct][j] + bea[ct]) + w.y * (accB[rt][ct][j] + beb[ct]);
          const size_t oi = (size_t)tk * DIM + n0 + ct * 16 + col_l;
          if (isbf) ((unsigned short*)outv)[oi] = f2bf_rne(o);
          else      ((float*)outv)[oi] = o;
        }
      }
    }
  }
}

extern "C" void kernel_launch(void* const* d_in, const int* in_sizes, int n_in,
                              void* d_out, int out_size, void* d_ws, size_t ws_size,
                              hipStream_t stream) {
  const void* xv  = d_in[0];   // [4,4096,1024] bf16 or fp32 (detected on-device)
  // d_in[1] router_mask: unused
  const void* Wev = d_in[2];   // [8,1024,1024]
  const void* bev = d_in[3];   // [8,1024]
  const void* Wgv = d_in[4];   // [1024,8]
  const void* bgv = d_in[5];   // [8]
  // d_in[6] top_k == 2

  char* ws = (char*)d_ws;
  int* cnt    = (int*)(ws + OFF_CNT);
  int* ntiles = (int*)(ws + OFF_NTILES);
  int* flag   = (int*)(ws + OFF_FLAG);
  int* tmap   = (int*)(ws + OFF_TMAP);
  float2* tokw = (float2*)(ws + OFF_TOKW);
  unsigned short* plist = (unsigned short*)(ws + OFF_PLIST);
  unsigned short* Wt    = (unsigned short*)(ws + OFF_WT);

  if (ws_size < (size_t)NEED_T3) return;  // cannot run at all; fail visibly, not fatally
  const int tier = (ws_size >= (size_t)NEED_T2) ? 2 : 3;

  zero_counters<<<1, 64, 0, stream>>>(cnt);
  detect_dtype<<<1, 256, 0, stream>>>((const unsigned int*)xv, flag);
  if (tier == 2) transpose_W<<<dim3(16, 16, 8), 256, 0, stream>>>(Wev, Wt, flag);
  gating<<<TOK / 4, 256, 0, stream>>>(xv, Wgv, bgv, flag, cnt, plist, tokw);
  build_tiles<<<1, 64, 0, stream>>>(cnt, tmap, ntiles);
  if (tier == 2)
    moe_gemm<2><<<dim3(16, 160), 256, 0, stream>>>(xv, Wt, Wev, bev, flag, cnt,
                                                   plist, tokw, ntiles, tmap, d_out);
  else
    moe_gemm<3><<<dim3(16, 160), 256, 0, stream>>>(xv, Wt, Wev, bev, flag, cnt,
                                                   plist, tokw, ntiles, tmap, d_out);
}

// Round 3
// 407.198 us; speedup vs baseline: 1.0528x; 1.0528x over previous
//
#include <hip/hip_runtime.h>

// MoE top-2, B=4 S=4096 D=1024 E=8.  router_mask/top_k unused (per reference).
//
// R3: LDS-bandwidth attack. Wave tile 64x64x2experts (128 acc VGPRs), block
// 128 tok x 128 cols, global_load_lds staging with source-side XOR swizzle,
// tile map computed in-block, zero+detect fused. 4 kernels total.

#define TOK 16384
#define DIM 1024
#define NE 8
#define NPAIR 28

typedef __attribute__((ext_vector_type(8))) short bf16x8;
typedef __attribute__((ext_vector_type(4))) float f32x4;

// ---- ws layout ----
#define OFF_CNT    0u
#define OFF_NTILES 128u
#define OFF_FLAG   132u
#define OFF_TOKW   1024u      // 16384 float2 -> ends 132096
#define OFF_PLIST  132096u    // 28*16384 ushort -> ends 1049600
#define OFF_WT     1049600u   // 16 MiB bf16 -> ends 17826816
#define NEED_T3    1049600u
#define NEED_T2    17826816u

__device__ __forceinline__ float bf2f(unsigned short u) {
  union { unsigned int i; float f; } c; c.i = ((unsigned int)u) << 16; return c.f;
}
__device__ __forceinline__ unsigned short f2bf_rne(float f) {
  union { float f; unsigned int i; } c; c.f = f;
  unsigned int i = c.i + 0x7fffu + ((c.i >> 16) & 1u);
  return (unsigned short)(i >> 16);
}
__device__ __forceinline__ unsigned int pk2(float lo, float hi) {
  union { float f; unsigned int i; } a, b; a.f = lo; b.f = hi;
  return ((b.i + 0x8000u) & 0xFFFF0000u) | ((a.i + 0x8000u) >> 16);
}

typedef const __attribute__((address_space(1))) unsigned int gas_uint;
typedef __attribute__((address_space(3))) unsigned int las_uint;
__device__ __forceinline__ void gl_lds16(const void* g, void* l) {
  __builtin_amdgcn_global_load_lds((gas_uint*)g, (las_uint*)l, 16, 0, 0);
}

// ---------------- init: zero counters + dtype detect ----------------
__global__ void init_detect(const unsigned int* __restrict__ xdw,
                            int* __restrict__ cnt, int* __restrict__ flag) {
  __shared__ int h;
  if (threadIdx.x == 0) h = 0;
  __syncthreads();
  if (threadIdx.x < 32) cnt[threadIdx.x] = 0;
  unsigned int idx = (threadIdx.x * 32749u + 7u) & 0x7FFFFFu;  // in-bounds both dtypes
  unsigned int b = (xdw[idx] >> 7) & 0xFFu;
  atomicAdd(&h, (b >= 112u && b <= 132u) ? 1 : 0);
  __syncthreads();
  if (threadIdx.x == 0) flag[0] = (h >= 128) ? 1 : 0;
}

// ---------------- W transpose: Wt[e][n][k] = bf16(We[e][k][n]) ----------------
__global__ __launch_bounds__(256) void transpose_W(const void* __restrict__ Wev,
                                                   unsigned short* __restrict__ Wt,
                                                   const int* __restrict__ flag) {
  const int isbf = *flag;
  __shared__ __align__(16) unsigned short tile[64 * 72];
  const int k0 = blockIdx.x * 64, n0 = blockIdx.y * 64;
  const size_t ebase = (size_t)blockIdx.z << 20;
  const int tid = threadIdx.x;
  const int r = tid >> 2;
  const int off = (tid & 3) * 16;
  unsigned short buf[16];
  if (isbf) {
    const unsigned short* s = (const unsigned short*)Wev + ebase + (size_t)(k0 + r) * DIM + n0 + off;
    *(uint4*)&buf[0] = *(const uint4*)s;
    *(uint4*)&buf[8] = *(const uint4*)(s + 8);
  } else {
    const float* s = (const float*)Wev + ebase + (size_t)(k0 + r) * DIM + n0 + off;
#pragma unroll
    for (int jj = 0; jj < 4; ++jj) {
      float4 f = *(const float4*)(s + jj * 4);
      buf[jj * 4 + 0] = f2bf_rne(f.x); buf[jj * 4 + 1] = f2bf_rne(f.y);
      buf[jj * 4 + 2] = f2bf_rne(f.z); buf[jj * 4 + 3] = f2bf_rne(f.w);
    }
  }
  *(uint4*)&tile[r * 72 + off] = *(uint4*)&buf[0];
  *(uint4*)&tile[r * 72 + off + 8] = *(uint4*)&buf[8];
  __syncthreads();
  const int n = tid >> 2, ko = (tid & 3) * 16;
  unsigned short obuf[16];
#pragma unroll
  for (int j = 0; j < 16; ++j) obuf[j] = tile[(ko + j) * 72 + n];
  unsigned short* dst = Wt + ebase + (size_t)(n0 + n) * DIM + k0 + ko;
  *(uint4*)dst = *(uint4*)&obuf[0];
  *(uint4*)(dst + 8) = *(uint4*)&obuf[8];
}

// ---------------- gating: one wave per token ----------------
__global__ __launch_bounds__(256) void gating(const void* __restrict__ xv,
                                              const void* __restrict__ Wgv,
                                              const void* __restrict__ bgv,
                                              const int* __restrict__ flag,
                                              int* __restrict__ cnt,
                                              unsigned short* __restrict__ plist,
                                              float2* __restrict__ tokw) {
  const int isbf = *flag;
  const int lane = threadIdx.x & 63;
  const int t = blockIdx.x * 4 + (threadIdx.x >> 6);
  float acc[NE];
#pragma unroll
  for (int e = 0; e < NE; ++e) acc[e] = 0.f;

  if (isbf) {
    const unsigned short* xp = (const unsigned short*)xv + (size_t)t * DIM + lane * 16;
#pragma unroll
    for (int u = 0; u < 2; ++u) {
      union { uint4 v; unsigned short s[8]; } xr; xr.v = *(const uint4*)(xp + u * 8);
#pragma unroll
      for (int j = 0; j < 8; ++j) {
        const int d = lane * 16 + u * 8 + j;
        union { uint4 v; unsigned short s[8]; } wg;
        wg.v = *(const uint4*)((const unsigned short*)Wgv + (size_t)d * 8);
        const float xf = bf2f(xr.s[j]);
#pragma unroll
        for (int e = 0; e < NE; ++e) acc[e] += xf * bf2f(wg.s[e]);
      }
    }
  } else {
    const float* xp = (const float*)xv + (size_t)t * DIM + lane * 16;
    float xr[16];
#pragma unroll
    for (int u = 0; u < 4; ++u) *(float4*)&xr[u * 4] = *(const float4*)(xp + u * 4);
#pragma unroll
    for (int j = 0; j < 16; ++j) {
      const int d = lane * 16 + j;
      const float* wr = (const float*)Wgv + (size_t)d * 8;
      float4 w0 = *(const float4*)wr, w1 = *(const float4*)(wr + 4);
      const float xf = xr[j];
      acc[0] += xf * w0.x; acc[1] += xf * w0.y; acc[2] += xf * w0.z; acc[3] += xf * w0.w;
      acc[4] += xf * w1.x; acc[5] += xf * w1.y; acc[6] += xf * w1.z; acc[7] += xf * w1.w;
    }
  }
#pragma unroll
  for (int m = 1; m < 64; m <<= 1) {
#pragma unroll
    for (int e = 0; e < NE; ++e) acc[e] += __shfl_xor(acc[e], m);
  }
  if (lane == 0) {
    if (isbf) {
      union { uint4 v; unsigned short s[8]; } bgv8; bgv8.v = *(const uint4*)bgv;
#pragma unroll
      for (int e = 0; e < NE; ++e) acc[e] += bf2f(bgv8.s[e]);
    } else {
      const float* bgp = (const float*)bgv;
#pragma unroll
      for (int e = 0; e < NE; ++e) acc[e] += bgp[e];
    }
    int e0 = 0; float v0 = acc[0];
#pragma unroll
    for (int e = 1; e < NE; ++e) if (acc[e] > v0) { v0 = acc[e]; e0 = e; }
    int e1 = -1; float v1 = -3.4e38f;
#pragma unroll
    for (int e = 0; e < NE; ++e) if (e != e0 && acc[e] > v1) { v1 = acc[e]; e1 = e; }
    const int a = e0 < e1 ? e0 : e1;
    const int b = e0 < e1 ? e1 : e0;
    const float wa = (a == e0) ? v0 : v1;
    const float wb = (a == e0) ? v1 : v0;
    const int pidx = a * 7 - (a * (a - 1)) / 2 + (b - a - 1);
    const int pos = atomicAdd(&cnt[pidx], 1);
    plist[pidx * TOK + pos] = (unsigned short)t;
    tokw[t] = make_float2(wa, wb);
  }
}

// ---------------- pair GEMM ----------------
// Block 256 thr = 2x2 waves. Tile: 128 tokens x 128 cols, both experts of the
// pair, BK=64. Wave tile 64x64x2exp -> acc 4x4x2 f32x4 = 128 VGPRs.
// LDS 48KB: A[128][64] + W[2*128][64], XOR-swizzled 16B chunks (conflict-free).
// Staging via global_load_lds (bf16 path); source-chunk permutation realizes
// the swizzle since the DMA dest is fixed at base + lane*16.
template <int TIER>
__global__ __launch_bounds__(256, 2) void moe_gemm(
    const void* __restrict__ xv, const unsigned short* __restrict__ Wt,
    const void* __restrict__ Wev, const void* __restrict__ bev,
    const int* __restrict__ flag, const int* __restrict__ cnt,
    const unsigned short* __restrict__ plist, const float2* __restrict__ tokw,
    void* __restrict__ outv) {
  // ---- in-block tile map: blockIdx.y -> (pair p, row-tile mt) ----
  const int y = blockIdx.y;
  int p = -1, mt = 0, acc8 = 0;
  for (int q = 0; q < NPAIR; ++q) {
    const int t = (cnt[q] + 127) >> 7;
    if (y < acc8 + t) { p = q; mt = y - acc8; break; }
    acc8 += t;
  }
  if (p < 0) return;
  const int count = cnt[p];
  int a = 0, rem = p;
  while (rem >= 7 - a) { rem -= 7 - a; ++a; }
  const int ea = a, eb = a + 1 + rem;
  const int isbf = *flag;

  const int tid = threadIdx.x;
  const int lane = tid & 63;
  const int w = tid >> 6;
  const int wr = w >> 1, wc = w & 1;
  const int n0 = blockIdx.x * 128;

  __shared__ __align__(16) unsigned short Alds[128 * 64];
  __shared__ __align__(16) unsigned short Wlds[256 * 64];  // [exp*128+n][k]

  const int csrc = (lane & 7) ^ (lane >> 3);  // source chunk for slot lane&7

  // ---- A staging bases (bf16 DMA path): load li covers rows w*32+li*8+(lane>>3)
  const char* aptr[4];
#pragma unroll
  for (int li = 0; li < 4; ++li) {
    int rg = mt * 128 + w * 32 + li * 8 + (lane >> 3);
    int rgc = rg < count ? rg : count - 1;
    int tok = (int)plist[p * TOK + rgc];
    aptr[li] = (const char*)xv + (size_t)tok * (DIM * 2) + csrc * 16;
  }
  // ---- W staging bases: combined row R = w*64+li*8+(lane>>3), exp=R>>7, n=R&127
  const char* wptr[8];
#pragma unroll
  for (int li = 0; li < 8; ++li) {
    int R = w * 64 + li * 8 + (lane >> 3);
    size_t e = (size_t)((R >> 7) ? eb : ea);
    int n = R & 127;
    wptr[li] = (const char*)Wt + (e << 21) + (size_t)(n0 + n) * (DIM * 2) + csrc * 16;
  }
  // ---- fp32 A fallback: row rF = tid>>1, chunks (tid&1)*4 .. +3
  const int rF = tid >> 1;
  const float* xrowF = nullptr;
  if (!isbf) {
    int rg = mt * 128 + rF;
    int rgc = rg < count ? rg : count - 1;
    xrowF = (const float*)xv + (size_t)plist[p * TOK + rgc] * DIM;
  }

  f32x4 accA[4][4], accB[4][4];
#pragma unroll
  for (int i = 0; i < 4; ++i)
#pragma unroll
    for (int j = 0; j < 4; ++j) { accA[i][j] = (f32x4){0,0,0,0}; accB[i][j] = (f32x4){0,0,0,0}; }

  for (int ks = 0; ks < DIM; ks += 64) {
    // ---- stage A ----
    if (isbf) {
#pragma unroll
      for (int li = 0; li < 4; ++li)
        gl_lds16(aptr[li] + ks * 2, (char*)Alds + (w * 32 + li * 8) * 128);
    } else {
#pragma unroll
      for (int i = 0; i < 4; ++i) {
        const int cst = (tid & 1) * 4 + i;
        const int cs = cst ^ (rF & 7);
        const float* s = xrowF + ks + cs * 8;
        float4 f0 = *(const float4*)s, f1 = *(const float4*)(s + 4);
        uint4 v;
        v.x = pk2(f0.x, f0.y); v.y = pk2(f0.z, f0.w);
        v.z = pk2(f1.x, f1.y); v.w = pk2(f1.z, f1.w);
        *(uint4*)&Alds[rF * 64 + cst * 8] = v;
      }
    }
    // ---- stage W ----
    if (TIER == 2) {
#pragma unroll
      for (int li = 0; li < 8; ++li)
        gl_lds16(wptr[li] + ks * 2, (char*)Wlds + (w * 64 + li * 8) * 128);
    } else {
      const int kk = tid >> 2, noff = (tid & 3) * 32;
#pragma unroll
      for (int h = 0; h < 2; ++h) {
        const size_t eb2 = (size_t)(h ? eb : ea) << 20;
        unsigned short wb[32];
        if (isbf) {
          const unsigned short* s = (const unsigned short*)Wev + eb2 + (size_t)(ks + kk) * DIM + n0 + noff;
#pragma unroll
          for (int jj = 0; jj < 4; ++jj) *(uint4*)&wb[jj * 8] = *(const uint4*)(s + jj * 8);
        } else {
          const float* s = (const float*)Wev + eb2 + (size_t)(ks + kk) * DIM + n0 + noff;
#pragma unroll
          for (int jj = 0; jj < 8; ++jj) {
            float4 f = *(const float4*)(s + jj * 4);
            unsigned int lo = pk2(f.x, f.y), hi = pk2(f.z, f.w);
            wb[jj * 4 + 0] = (unsigned short)(lo & 0xFFFF);
            wb[jj * 4 + 1] = (unsigned short)(lo >> 16);
            wb[jj * 4 + 2] = (unsigned short)(hi & 0xFFFF);
            wb[jj * 4 + 3] = (unsigned short)(hi >> 16);
          }
        }
        const int chunk = kk >> 3, kin = kk & 7;
#pragma unroll
        for (int j = 0; j < 32; ++j) {
          const int n = noff + j;
          Wlds[(h * 128 + n) * 64 + ((chunk ^ (n & 7)) << 3) + kin] = wb[j];
        }
      }
    }
    __syncthreads();
    // ---- MFMA: 2 ksteps x (4 A reads + 8 B reads + 32 MFMAs) ----
    const int rl = lane & 15;
#pragma unroll
    for (int kst = 0; kst < 2; ++kst) {
      const int chunk = kst * 4 + (lane >> 4);
      bf16x8 af[4];
#pragma unroll
      for (int m4 = 0; m4 < 4; ++m4) {
        const int r = wr * 64 + m4 * 16 + rl;
        af[m4] = *(const bf16x8*)&Alds[r * 64 + ((chunk ^ (r & 7)) << 3)];
      }
#pragma unroll
      for (int nt = 0; nt < 4; ++nt) {
        const int n = wc * 64 + nt * 16 + rl;
        const int wo = (chunk ^ (n & 7)) << 3;
        bf16x8 bA = *(const bf16x8*)&Wlds[n * 64 + wo];
        bf16x8 bB = *(const bf16x8*)&Wlds[(128 + n) * 64 + wo];
#pragma unroll
        for (int m4 = 0; m4 < 4; ++m4) {
          accA[m4][nt] = __builtin_amdgcn_mfma_f32_16x16x32_bf16(af[m4], bA, accA[m4][nt], 0, 0, 0);
          accB[m4][nt] = __builtin_amdgcn_mfma_f32_16x16x32_bf16(af[m4], bB, accB[m4][nt], 0, 0, 0);
        }
      }
    }
    __syncthreads();
  }

  // ---- epilogue: out = wa*(XA + be_a) + wb*(XB + be_b) ----
  const int col_l = lane & 15, quad = lane >> 4;
  float bea[4], beb[4];
#pragma unroll
  for (int nt = 0; nt < 4; ++nt) {
    const int col = n0 + wc * 64 + nt * 16 + col_l;
    if (isbf) {
      bea[nt] = bf2f(((const unsigned short*)bev)[ea * DIM + col]);
      beb[nt] = bf2f(((const unsigned short*)bev)[eb * DIM + col]);
    } else {
      bea[nt] = ((const float*)bev)[ea * DIM + col];
      beb[nt] = ((const float*)bev)[eb * DIM + col];
    }
  }
#pragma unroll
  for (int m4 = 0; m4 < 4; ++m4) {
#pragma unroll
    for (int j = 0; j < 4; ++j) {
      const int rg = mt * 128 + wr * 64 + m4 * 16 + quad * 4 + j;
      if (rg < count) {
        const int tk = (int)plist[p * TOK + rg];
        const float2 wt2 = tokw[tk];
#pragma unroll
        for (int nt = 0; nt < 4; ++nt) {
          const float o = wt2.x * (accA[m4][nt][j] + bea[nt]) + wt2.y * (accB[m4][nt][j] + beb[nt]);
          const size_t oi = (size_t)tk * DIM + n0 + wc * 64 + nt * 16 + col_l;
          if (isbf) ((unsigned short*)outv)[oi] = f2bf_rne(o);
          else      ((float*)outv)[oi] = o;
        }
      }
    }
  }
}

extern "C" void kernel_launch(void* const* d_in, const int* in_sizes, int n_in,
                              void* d_out, int out_size, void* d_ws, size_t ws_size,
                              hipStream_t stream) {
  const void* xv  = d_in[0];
  const void* Wev = d_in[2];
  const void* bev = d_in[3];
  const void* Wgv = d_in[4];
  const void* bgv = d_in[5];

  char* ws = (char*)d_ws;
  int* cnt    = (int*)(ws + OFF_CNT);
  int* flag   = (int*)(ws + OFF_FLAG);
  float2* tokw = (float2*)(ws + OFF_TOKW);
  unsigned short* plist = (unsigned short*)(ws + OFF_PLIST);
  unsigned short* Wt    = (unsigned short*)(ws + OFF_WT);

  if (ws_size < (size_t)NEED_T3) return;
  const int tier = (ws_size >= (size_t)NEED_T2) ? 2 : 3;

  init_detect<<<1, 256, 0, stream>>>((const unsigned int*)xv, cnt, flag);
  if (tier == 2) transpose_W<<<dim3(16, 16, 8), 256, 0, stream>>>(Wev, Wt, flag);
  gating<<<TOK / 4, 256, 0, stream>>>(xv, Wgv, bgv, flag, cnt, plist, tokw);
  if (tier == 2)
    moe_gemm<2><<<dim3(8, 160), 256, 0, stream>>>(xv, Wt, Wev, bev, flag, cnt,
                                                  plist, tokw, d_out);
  else
    moe_gemm<3><<<dim3(8, 160), 256, 0, stream>>>(xv, Wt, Wev, bev, flag, cnt,
                                                  plist, tokw, d_out);
}